// Round 2
// baseline (527.912 us; speedup 1.0000x reference)
//
#include <hip/hip_runtime.h>
#include <math.h>

// Problem constants (from reference)
constexpr int N_NODES = 50000;
constexpr int E_EDGES = 800000;
constexpr int E_TOT   = E_EDGES + N_NODES;   // 850000 with self loops
constexpr int D_IN    = 128;
constexpr int D_HID   = 64;   // HID == OUT == 64
constexpr float NEG_SLOPE = 0.2f;

// ---------------- CSR build ----------------

// one pass over the edge list: histogram of dst + emit edge_index-with-self-loops
__global__ __launch_bounds__(256)
void k_hist_ei(const int* __restrict__ ei, int* __restrict__ counts,
               float* __restrict__ out_ei) {
    int k = blockIdx.x * blockDim.x + threadIdx.x;
    if (k >= E_TOT) return;
    int src, dst;
    if (k < E_EDGES) { src = ei[k]; dst = ei[E_EDGES + k]; }
    else             { src = dst = k - E_EDGES; }
    out_ei[k]         = (float)src;
    out_ei[E_TOT + k] = (float)dst;
    atomicAdd(&counts[dst], 1);
}

// single block of 1024 threads: exclusive scan of counts -> rowptr, cursor
__global__ __launch_bounds__(1024)
void k_scan(int* __restrict__ counts_cursor, int* __restrict__ rowptr) {
    __shared__ int sums[1024];
    const int t = threadIdx.x;
    constexpr int CHUNK = (N_NODES + 1023) / 1024;   // 49
    int lo = t * CHUNK, hi = min(lo + CHUNK, N_NODES);
    int s = 0;
    for (int i = lo; i < hi; ++i) s += counts_cursor[i];
    sums[t] = s;
    __syncthreads();
    // Hillis-Steele inclusive scan over 1024 partials
    for (int off = 1; off < 1024; off <<= 1) {
        int v = (t >= off) ? sums[t - off] : 0;
        __syncthreads();
        sums[t] += v;
        __syncthreads();
    }
    int base = (t == 0) ? 0 : sums[t - 1];
    for (int i = lo; i < hi; ++i) {
        int c = counts_cursor[i];
        rowptr[i] = base;
        counts_cursor[i] = base;   // cursor init (aliases counts)
        base += c;
    }
    if (t == 1023) rowptr[N_NODES] = base;   // == E_TOT
}

__global__ __launch_bounds__(256)
void k_scatter(const int* __restrict__ ei, int* __restrict__ cursor,
               int* __restrict__ csr_src, int* __restrict__ csr_eid) {
    int k = blockIdx.x * blockDim.x + threadIdx.x;
    if (k >= E_TOT) return;
    int src, dst;
    if (k < E_EDGES) { src = ei[k]; dst = ei[E_EDGES + k]; }
    else             { src = dst = k - E_EDGES; }
    int pos = atomicAdd(&cursor[dst], 1);
    csr_src[pos] = src;
    csr_eid[pos] = k;
}

// ---------------- dense: h = x @ W  (+ per-node attention logits) ----------------

// layer 1: x [N,128] @ W1 [128,64]; one wave per node, lane = output col
__global__ __launch_bounds__(256)
void k_gemm1(const float* __restrict__ x, const float* __restrict__ W,
             const float* __restrict__ a_s, const float* __restrict__ a_d,
             float* __restrict__ h, float* __restrict__ es, float* __restrict__ ed) {
    int wave = threadIdx.x >> 6, lane = threadIdx.x & 63;
    int node = blockIdx.x * 4 + wave;
    if (node >= N_NODES) return;
    float x0 = x[node * D_IN + lane];
    float x1 = x[node * D_IN + 64 + lane];
    float acc = 0.f;
    #pragma unroll
    for (int k = 0; k < 64; ++k)
        acc = fmaf(__shfl(x0, k), W[k * D_HID + lane], acc);
    #pragma unroll
    for (int k = 0; k < 64; ++k)
        acc = fmaf(__shfl(x1, k), W[(64 + k) * D_HID + lane], acc);
    h[node * D_HID + lane] = acc;
    float vs = acc * a_s[lane];
    float vd = acc * a_d[lane];
    #pragma unroll
    for (int off = 32; off; off >>= 1) {
        vs += __shfl_xor(vs, off);
        vd += __shfl_xor(vd, off);
    }
    if (lane == 0) { es[node] = vs; ed[node] = vd; }
}

// layer 2: hin [N,64] @ W2 [64,64]
__global__ __launch_bounds__(256)
void k_gemm2(const float* __restrict__ hin, const float* __restrict__ W,
             const float* __restrict__ a_s, const float* __restrict__ a_d,
             float* __restrict__ h, float* __restrict__ es, float* __restrict__ ed) {
    int wave = threadIdx.x >> 6, lane = threadIdx.x & 63;
    int node = blockIdx.x * 4 + wave;
    if (node >= N_NODES) return;
    float x0 = hin[node * D_HID + lane];
    float acc = 0.f;
    #pragma unroll
    for (int k = 0; k < 64; ++k)
        acc = fmaf(__shfl(x0, k), W[k * D_HID + lane], acc);
    h[node * D_HID + lane] = acc;
    float vs = acc * a_s[lane];
    float vd = acc * a_d[lane];
    #pragma unroll
    for (int off = 32; off; off >>= 1) {
        vs += __shfl_xor(vs, off);
        vd += __shfl_xor(vd, off);
    }
    if (lane == 0) { es[node] = vs; ed[node] = vd; }
}

// ---------------- sparse: segment softmax + weighted aggregation ----------------
// one wave per destination node

template<bool RELU, bool WRITE_ALPHA>
__global__ __launch_bounds__(256)
void k_agg(const float* __restrict__ h, const float* __restrict__ es,
           const float* __restrict__ ed, const int* __restrict__ rowptr,
           const int* __restrict__ csr_src, const int* __restrict__ csr_eid,
           const float* __restrict__ bias, float* __restrict__ out,
           float* __restrict__ alpha_out) {
    int wave = threadIdx.x >> 6, lane = threadIdx.x & 63;
    int node = blockIdx.x * 4 + wave;
    if (node >= N_NODES) return;
    int lo  = __builtin_amdgcn_readfirstlane(rowptr[node]);
    int deg = __builtin_amdgcn_readfirstlane(rowptr[node + 1]) - lo;
    float edv = ed[node];

    if (deg <= 64) {
        // ---- fast path: lane-parallel logits, register-resident softmax ----
        int   s = 0, eid = 0;
        float e = -INFINITY;
        if (lane < deg) {
            s   = csr_src[lo + lane];
            if (WRITE_ALPHA) eid = csr_eid[lo + lane];
            e = es[s] + edv;
            e = (e >= 0.f) ? e : NEG_SLOPE * e;
        }
        float m = e;
        #pragma unroll
        for (int off = 32; off; off >>= 1) m = fmaxf(m, __shfl_xor(m, off));
        float ex = (lane < deg) ? __expf(e - m) : 0.f;
        float z = ex;
        #pragma unroll
        for (int off = 32; off; off >>= 1) z += __shfl_xor(z, off);
        float inv = 1.f / z;

        float acc = 0.f;
        for (int j = 0; j < deg; ++j) {
            int   sj  = __shfl(s, j);
            float exj = __shfl(ex, j);
            acc = fmaf(exj, h[sj * D_HID + lane], acc);
        }
        float res = fmaf(acc, inv, bias[lane]);
        if (RELU) res = fmaxf(res, 0.f);
        out[node * D_HID + lane] = res;
        if (WRITE_ALPHA && lane < deg) alpha_out[eid] = ex * inv;
    } else {
        // ---- fallback: serial 3-pass (degree > 64; effectively never) ----
        int hi = lo + deg;
        float m = -INFINITY;
        for (int j = lo; j < hi; ++j) {
            float e = es[csr_src[j]] + edv;
            e = (e >= 0.f) ? e : NEG_SLOPE * e;
            m = fmaxf(m, e);
        }
        float z = 0.f, acc = 0.f;
        for (int j = lo; j < hi; ++j) {
            int s = csr_src[j];
            float e = es[s] + edv;
            e = (e >= 0.f) ? e : NEG_SLOPE * e;
            float ex = __expf(e - m);
            z += ex;
            acc = fmaf(ex, h[s * D_HID + lane], acc);
        }
        float inv = 1.f / z;
        float res = fmaf(acc, inv, bias[lane]);
        if (RELU) res = fmaxf(res, 0.f);
        out[node * D_HID + lane] = res;
        if (WRITE_ALPHA) {
            for (int j = lo + lane; j < hi; j += 64) {
                int s = csr_src[j];
                float e = es[s] + edv;
                e = (e >= 0.f) ? e : NEG_SLOPE * e;
                alpha_out[csr_eid[j]] = __expf(e - m) * inv;
            }
        }
    }
}

// ---------------- launch ----------------

extern "C" void kernel_launch(void* const* d_in, const int* in_sizes, int n_in,
                              void* d_out, int out_size, void* d_ws, size_t ws_size,
                              hipStream_t stream) {
    const float* x    = (const float*)d_in[0];
    const int*   ei   = (const int*)d_in[1];
    const float* W1   = (const float*)d_in[2];
    const float* as1  = (const float*)d_in[3];
    const float* ad1  = (const float*)d_in[4];
    const float* b1   = (const float*)d_in[5];
    const float* W2   = (const float*)d_in[6];
    const float* as2  = (const float*)d_in[7];
    const float* ad2  = (const float*)d_in[8];
    const float* b2   = (const float*)d_in[9];
    float* out = (float*)d_out;

    // carve workspace (~33.5 MB)
    size_t off = 0;
    auto carve = [&](size_t bytes) -> void* {
        void* p = (char*)d_ws + off;
        off += (bytes + 255) & ~(size_t)255;
        return p;
    };
    int*   cursor  = (int*)carve((size_t)N_NODES * 4);          // counts, then cursor
    int*   rowptr  = (int*)carve((size_t)(N_NODES + 1) * 4);
    int*   csr_src = (int*)carve((size_t)E_TOT * 4);
    int*   csr_eid = (int*)carve((size_t)E_TOT * 4);
    float* h1      = (float*)carve((size_t)N_NODES * D_HID * 4); // reused as h2lin
    float* h1a     = (float*)carve((size_t)N_NODES * D_HID * 4);
    float* es      = (float*)carve((size_t)N_NODES * 4);         // reused layer 2
    float* edv     = (float*)carve((size_t)N_NODES * 4);         // reused layer 2

    float* out_ei    = out;                     // [2*E_TOT]
    float* out_alpha = out + 2 * (size_t)E_TOT; // [E_TOT]
    float* out_h2    = out + 3 * (size_t)E_TOT; // [N*64]

    const int eb = (E_TOT + 255) / 256;
    const int nb = (N_NODES + 3) / 4;

    // CSR build (shared by both layers)
    hipMemsetAsync(cursor, 0, (size_t)N_NODES * 4, stream);
    k_hist_ei<<<eb, 256, 0, stream>>>(ei, cursor, out_ei);
    k_scan<<<1, 1024, 0, stream>>>(cursor, rowptr);
    k_scatter<<<eb, 256, 0, stream>>>(ei, cursor, csr_src, csr_eid);

    // layer 1
    k_gemm1<<<nb, 256, 0, stream>>>(x, W1, as1, ad1, h1, es, edv);
    k_agg<true, true><<<nb, 256, 0, stream>>>(h1, es, edv, rowptr, csr_src, csr_eid,
                                              b1, h1a, out_alpha);
    // layer 2 (h2lin aliases h1; es/edv reused)
    k_gemm2<<<nb, 256, 0, stream>>>(h1a, W2, as2, ad2, h1, es, edv);
    k_agg<false, false><<<nb, 256, 0, stream>>>(h1, es, edv, rowptr, csr_src, csr_eid,
                                                b2, out_h2, nullptr);
}

// Round 3
// 429.190 us; speedup vs baseline: 1.2300x; 1.2300x over previous
//
#include <hip/hip_runtime.h>
#include <math.h>

// Problem constants (from reference)
constexpr int N_NODES = 50000;
constexpr int E_EDGES = 800000;
constexpr int E_TOT   = E_EDGES + N_NODES;   // 850000 with self loops
constexpr int D_IN    = 128;
constexpr int D_HID   = 64;   // HID == OUT == 64
constexpr float NEG_SLOPE = 0.2f;

constexpr int SCAN_B  = 256;
constexpr int SCAN_NB = (N_NODES + SCAN_B - 1) / SCAN_B;   // 196

// ---------------- CSR build ----------------

// one pass over the edge list: histogram of dst + emit edge_index-with-self-loops
__global__ __launch_bounds__(256)
void k_hist_ei(const int* __restrict__ ei, int* __restrict__ counts,
               float* __restrict__ out_ei) {
    int k = blockIdx.x * blockDim.x + threadIdx.x;
    if (k >= E_TOT) return;
    int src, dst;
    if (k < E_EDGES) { src = ei[k]; dst = ei[E_EDGES + k]; }
    else             { src = dst = k - E_EDGES; }
    out_ei[k]         = (float)src;
    out_ei[E_TOT + k] = (float)dst;
    atomicAdd(&counts[dst], 1);
}

// scan phase A: per-block sums of counts
__global__ __launch_bounds__(256)
void k_scan_a(const int* __restrict__ counts, int* __restrict__ blocksum) {
    int i = blockIdx.x * SCAN_B + threadIdx.x;
    int lane = threadIdx.x & 63, wave = threadIdx.x >> 6;
    int v = (i < N_NODES) ? counts[i] : 0;
    #pragma unroll
    for (int off = 32; off; off >>= 1) v += __shfl_xor(v, off);
    __shared__ int ws[4];
    if (lane == 0) ws[wave] = v;
    __syncthreads();
    if (threadIdx.x == 0)
        blocksum[blockIdx.x] = ws[0] + ws[1] + ws[2] + ws[3];
}

// scan phase B: single small block scans the 196 block sums (exclusive, in place)
__global__ __launch_bounds__(256)
void k_scan_b(int* __restrict__ blocksum, int* __restrict__ rowptr) {
    __shared__ int s[SCAN_B];
    int t = threadIdx.x;
    int v = (t < SCAN_NB) ? blocksum[t] : 0;
    s[t] = v;
    __syncthreads();
    #pragma unroll
    for (int off = 1; off < SCAN_B; off <<= 1) {
        int u = (t >= off) ? s[t - off] : 0;
        __syncthreads();
        s[t] += u;
        __syncthreads();
    }
    if (t < SCAN_NB) blocksum[t] = s[t] - v;      // exclusive block base
    if (t == SCAN_B - 1) rowptr[N_NODES] = s[SCAN_B - 1];   // grand total == E_TOT
}

// scan phase C: in-block exclusive scan + block base -> rowptr & cursor init
__global__ __launch_bounds__(256)
void k_scan_c(int* __restrict__ counts_cursor, const int* __restrict__ blocksum,
              int* __restrict__ rowptr) {
    __shared__ int s[SCAN_B];
    int t = threadIdx.x;
    int i = blockIdx.x * SCAN_B + t;
    int v = (i < N_NODES) ? counts_cursor[i] : 0;
    s[t] = v;
    __syncthreads();
    #pragma unroll
    for (int off = 1; off < SCAN_B; off <<= 1) {
        int u = (t >= off) ? s[t - off] : 0;
        __syncthreads();
        s[t] += u;
        __syncthreads();
    }
    if (i < N_NODES) {
        int excl = s[t] - v + blocksum[blockIdx.x];
        rowptr[i] = excl;
        counts_cursor[i] = excl;   // cursor init (aliases counts)
    }
}

__global__ __launch_bounds__(256)
void k_scatter(const int* __restrict__ ei, int* __restrict__ cursor,
               int* __restrict__ csr_src, int* __restrict__ csr_eid) {
    int k = blockIdx.x * blockDim.x + threadIdx.x;
    if (k >= E_TOT) return;
    int src, dst;
    if (k < E_EDGES) { src = ei[k]; dst = ei[E_EDGES + k]; }
    else             { src = dst = k - E_EDGES; }
    int pos = atomicAdd(&cursor[dst], 1);
    csr_src[pos] = src;
    csr_eid[pos] = k;
}

// ---------------- dense: h = x @ W  (+ per-node attention logits) ----------------

// layer 1: x [N,128] @ W1 [128,64]; one wave per node, lane = output col
__global__ __launch_bounds__(256)
void k_gemm1(const float* __restrict__ x, const float* __restrict__ W,
             const float* __restrict__ a_s, const float* __restrict__ a_d,
             float* __restrict__ h, float* __restrict__ es, float* __restrict__ ed) {
    int wave = threadIdx.x >> 6, lane = threadIdx.x & 63;
    int node = blockIdx.x * 4 + wave;
    if (node >= N_NODES) return;
    float x0 = x[node * D_IN + lane];
    float x1 = x[node * D_IN + 64 + lane];
    float acc0 = 0.f, acc1 = 0.f;     // two chains to halve dep-latency exposure
    #pragma unroll
    for (int k = 0; k < 64; k += 2) {
        acc0 = fmaf(__shfl(x0, k),     W[k * D_HID + lane],       acc0);
        acc1 = fmaf(__shfl(x0, k + 1), W[(k + 1) * D_HID + lane], acc1);
    }
    #pragma unroll
    for (int k = 0; k < 64; k += 2) {
        acc0 = fmaf(__shfl(x1, k),     W[(64 + k) * D_HID + lane],     acc0);
        acc1 = fmaf(__shfl(x1, k + 1), W[(64 + k + 1) * D_HID + lane], acc1);
    }
    float acc = acc0 + acc1;
    h[node * D_HID + lane] = acc;
    float vs = acc * a_s[lane];
    float vd = acc * a_d[lane];
    #pragma unroll
    for (int off = 32; off; off >>= 1) {
        vs += __shfl_xor(vs, off);
        vd += __shfl_xor(vd, off);
    }
    if (lane == 0) { es[node] = vs; ed[node] = vd; }
}

// layer 2: hin [N,64] @ W2 [64,64]
__global__ __launch_bounds__(256)
void k_gemm2(const float* __restrict__ hin, const float* __restrict__ W,
             const float* __restrict__ a_s, const float* __restrict__ a_d,
             float* __restrict__ h, float* __restrict__ es, float* __restrict__ ed) {
    int wave = threadIdx.x >> 6, lane = threadIdx.x & 63;
    int node = blockIdx.x * 4 + wave;
    if (node >= N_NODES) return;
    float x0 = hin[node * D_HID + lane];
    float acc0 = 0.f, acc1 = 0.f;
    #pragma unroll
    for (int k = 0; k < 64; k += 2) {
        acc0 = fmaf(__shfl(x0, k),     W[k * D_HID + lane],       acc0);
        acc1 = fmaf(__shfl(x0, k + 1), W[(k + 1) * D_HID + lane], acc1);
    }
    float acc = acc0 + acc1;
    h[node * D_HID + lane] = acc;
    float vs = acc * a_s[lane];
    float vd = acc * a_d[lane];
    #pragma unroll
    for (int off = 32; off; off >>= 1) {
        vs += __shfl_xor(vs, off);
        vd += __shfl_xor(vd, off);
    }
    if (lane == 0) { es[node] = vs; ed[node] = vd; }
}

// ---------------- sparse: segment softmax + weighted aggregation ----------------
// one wave per destination node

template<bool RELU, bool WRITE_ALPHA>
__global__ __launch_bounds__(256)
void k_agg(const float* __restrict__ h, const float* __restrict__ es,
           const float* __restrict__ ed, const int* __restrict__ rowptr,
           const int* __restrict__ csr_src, const int* __restrict__ csr_eid,
           const float* __restrict__ bias, float* __restrict__ out,
           float* __restrict__ alpha_out) {
    int wave = threadIdx.x >> 6, lane = threadIdx.x & 63;
    int node = blockIdx.x * 4 + wave;
    if (node >= N_NODES) return;
    int lo  = __builtin_amdgcn_readfirstlane(rowptr[node]);
    int deg = __builtin_amdgcn_readfirstlane(rowptr[node + 1]) - lo;
    float edv = ed[node];

    if (deg <= 64) {
        // ---- fast path: lane-parallel logits, register-resident softmax ----
        int   s = 0, eid = 0;
        float e = -INFINITY;
        if (lane < deg) {
            s   = csr_src[lo + lane];
            if (WRITE_ALPHA) eid = csr_eid[lo + lane];
            e = es[s] + edv;
            e = (e >= 0.f) ? e : NEG_SLOPE * e;
        }
        float m = e;
        #pragma unroll
        for (int off = 32; off; off >>= 1) m = fmaxf(m, __shfl_xor(m, off));
        float ex = (lane < deg) ? __expf(e - m) : 0.f;
        float z = ex;
        #pragma unroll
        for (int off = 32; off; off >>= 1) z += __shfl_xor(z, off);
        float inv = 1.f / z;

        float acc = 0.f;
        for (int j = 0; j < deg; ++j) {
            int   sj  = __shfl(s, j);
            float exj = __shfl(ex, j);
            acc = fmaf(exj, h[sj * D_HID + lane], acc);
        }
        float res = fmaf(acc, inv, bias[lane]);
        if (RELU) res = fmaxf(res, 0.f);
        out[node * D_HID + lane] = res;
        if (WRITE_ALPHA && lane < deg) alpha_out[eid] = ex * inv;
    } else {
        // ---- fallback: serial 3-pass (degree > 64; effectively never) ----
        int hi = lo + deg;
        float m = -INFINITY;
        for (int j = lo; j < hi; ++j) {
            float e = es[csr_src[j]] + edv;
            e = (e >= 0.f) ? e : NEG_SLOPE * e;
            m = fmaxf(m, e);
        }
        float z = 0.f, acc = 0.f;
        for (int j = lo; j < hi; ++j) {
            int s = csr_src[j];
            float e = es[s] + edv;
            e = (e >= 0.f) ? e : NEG_SLOPE * e;
            float ex = __expf(e - m);
            z += ex;
            acc = fmaf(ex, h[s * D_HID + lane], acc);
        }
        float inv = 1.f / z;
        float res = fmaf(acc, inv, bias[lane]);
        if (RELU) res = fmaxf(res, 0.f);
        out[node * D_HID + lane] = res;
        if (WRITE_ALPHA) {
            for (int j = lo + lane; j < hi; j += 64) {
                int s = csr_src[j];
                float e = es[s] + edv;
                e = (e >= 0.f) ? e : NEG_SLOPE * e;
                alpha_out[csr_eid[j]] = __expf(e - m) * inv;
            }
        }
    }
}

// ---------------- launch ----------------

extern "C" void kernel_launch(void* const* d_in, const int* in_sizes, int n_in,
                              void* d_out, int out_size, void* d_ws, size_t ws_size,
                              hipStream_t stream) {
    const float* x    = (const float*)d_in[0];
    const int*   ei   = (const int*)d_in[1];
    const float* W1   = (const float*)d_in[2];
    const float* as1  = (const float*)d_in[3];
    const float* ad1  = (const float*)d_in[4];
    const float* b1   = (const float*)d_in[5];
    const float* W2   = (const float*)d_in[6];
    const float* as2  = (const float*)d_in[7];
    const float* ad2  = (const float*)d_in[8];
    const float* b2   = (const float*)d_in[9];
    float* out = (float*)d_out;

    // carve workspace (~34 MB)
    size_t off = 0;
    auto carve = [&](size_t bytes) -> void* {
        void* p = (char*)d_ws + off;
        off += (bytes + 255) & ~(size_t)255;
        return p;
    };
    int*   cursor   = (int*)carve((size_t)N_NODES * 4);          // counts, then cursor
    int*   rowptr   = (int*)carve((size_t)(N_NODES + 1) * 4);
    int*   blocksum = (int*)carve((size_t)SCAN_NB * 4);
    int*   csr_src  = (int*)carve((size_t)E_TOT * 4);
    int*   csr_eid  = (int*)carve((size_t)E_TOT * 4);
    float* h1       = (float*)carve((size_t)N_NODES * D_HID * 4); // reused as h2lin
    float* h1a      = (float*)carve((size_t)N_NODES * D_HID * 4);
    float* es       = (float*)carve((size_t)N_NODES * 4);         // reused layer 2
    float* edv      = (float*)carve((size_t)N_NODES * 4);         // reused layer 2

    float* out_ei    = out;                     // [2*E_TOT]
    float* out_alpha = out + 2 * (size_t)E_TOT; // [E_TOT]
    float* out_h2    = out + 3 * (size_t)E_TOT; // [N*64]

    const int eb = (E_TOT + 255) / 256;
    const int nb = (N_NODES + 3) / 4;

    // CSR build (shared by both layers)
    hipMemsetAsync(cursor, 0, (size_t)N_NODES * 4, stream);
    k_hist_ei<<<eb, 256, 0, stream>>>(ei, cursor, out_ei);
    k_scan_a<<<SCAN_NB, SCAN_B, 0, stream>>>(cursor, blocksum);
    k_scan_b<<<1, SCAN_B, 0, stream>>>(blocksum, rowptr);
    k_scan_c<<<SCAN_NB, SCAN_B, 0, stream>>>(cursor, blocksum, rowptr);
    k_scatter<<<eb, 256, 0, stream>>>(ei, cursor, csr_src, csr_eid);

    // layer 1
    k_gemm1<<<nb, 256, 0, stream>>>(x, W1, as1, ad1, h1, es, edv);
    k_agg<true, true><<<nb, 256, 0, stream>>>(h1, es, edv, rowptr, csr_src, csr_eid,
                                              b1, h1a, out_alpha);
    // layer 2 (h2lin aliases h1; es/edv reused)
    k_gemm2<<<nb, 256, 0, stream>>>(h1a, W2, as2, ad2, h1, es, edv);
    k_agg<false, false><<<nb, 256, 0, stream>>>(h1, es, edv, rowptr, csr_src, csr_eid,
                                                b2, out_h2, nullptr);
}

// Round 8
// 308.126 us; speedup vs baseline: 1.7133x; 1.3929x over previous
//
#include <hip/hip_runtime.h>
#include <math.h>

// Problem constants (from reference)
constexpr int N_NODES = 50000;
constexpr int E_EDGES = 800000;
constexpr int E_TOT   = E_EDGES + N_NODES;   // 850000 with self loops
constexpr int D_IN    = 128;
constexpr int D_HID   = 64;   // HID == OUT == 64
constexpr float NEG_SLOPE = 0.2f;

constexpr int SCAN_B  = 256;
constexpr int SCAN_NB = (N_NODES + SCAN_B - 1) / SCAN_B;   // 196

// ---------------- CSR build ----------------

// one pass over the edge list: histogram of dst + emit edge_index-with-self-loops
__global__ __launch_bounds__(256)
void k_hist_ei(const int* __restrict__ ei, int* __restrict__ counts,
               float* __restrict__ out_ei) {
    int k = blockIdx.x * blockDim.x + threadIdx.x;
    if (k >= E_TOT) return;
    int src, dst;
    if (k < E_EDGES) { src = ei[k]; dst = ei[E_EDGES + k]; }
    else             { src = dst = k - E_EDGES; }
    out_ei[k]         = (float)src;
    out_ei[E_TOT + k] = (float)dst;
    atomicAdd(&counts[dst], 1);
}

// scan phase A: per-block sums of counts
__global__ __launch_bounds__(256)
void k_scan_a(const int* __restrict__ counts, int* __restrict__ blocksum) {
    int i = blockIdx.x * SCAN_B + threadIdx.x;
    int lane = threadIdx.x & 63, wave = threadIdx.x >> 6;
    int v = (i < N_NODES) ? counts[i] : 0;
    #pragma unroll
    for (int off = 32; off; off >>= 1) v += __shfl_xor(v, off);
    __shared__ int ws[4];
    if (lane == 0) ws[wave] = v;
    __syncthreads();
    if (threadIdx.x == 0)
        blocksum[blockIdx.x] = ws[0] + ws[1] + ws[2] + ws[3];
}

// scan phase B: single small block scans the 196 block sums (exclusive, in place)
__global__ __launch_bounds__(256)
void k_scan_b(int* __restrict__ blocksum, int* __restrict__ rowptr) {
    __shared__ int s[SCAN_B];
    int t = threadIdx.x;
    int v = (t < SCAN_NB) ? blocksum[t] : 0;
    s[t] = v;
    __syncthreads();
    #pragma unroll
    for (int off = 1; off < SCAN_B; off <<= 1) {
        int u = (t >= off) ? s[t - off] : 0;
        __syncthreads();
        s[t] += u;
        __syncthreads();
    }
    if (t < SCAN_NB) blocksum[t] = s[t] - v;      // exclusive block base
    if (t == SCAN_B - 1) rowptr[N_NODES] = s[SCAN_B - 1];   // grand total == E_TOT
}

// scan phase C: in-block exclusive scan + block base -> rowptr & cursor init
__global__ __launch_bounds__(256)
void k_scan_c(int* __restrict__ counts_cursor, const int* __restrict__ blocksum,
              int* __restrict__ rowptr) {
    __shared__ int s[SCAN_B];
    int t = threadIdx.x;
    int i = blockIdx.x * SCAN_B + t;
    int v = (i < N_NODES) ? counts_cursor[i] : 0;
    s[t] = v;
    __syncthreads();
    #pragma unroll
    for (int off = 1; off < SCAN_B; off <<= 1) {
        int u = (t >= off) ? s[t - off] : 0;
        __syncthreads();
        s[t] += u;
        __syncthreads();
    }
    if (i < N_NODES) {
        int excl = s[t] - v + blocksum[blockIdx.x];
        rowptr[i] = excl;
        counts_cursor[i] = excl;   // cursor init (aliases counts)
    }
}

__global__ __launch_bounds__(256)
void k_scatter(const int* __restrict__ ei, int* __restrict__ cursor,
               int* __restrict__ csr_src, int* __restrict__ csr_eid) {
    int k = blockIdx.x * blockDim.x + threadIdx.x;
    if (k >= E_TOT) return;
    int src, dst;
    if (k < E_EDGES) { src = ei[k]; dst = ei[E_EDGES + k]; }
    else             { src = dst = k - E_EDGES; }
    int pos = atomicAdd(&cursor[dst], 1);
    csr_src[pos] = src;
    csr_eid[pos] = k;
}

// ---------------- dense: h = x @ W  (+ per-node attention logits) ----------------
// Register-tiled GEMM: block = 256 threads -> 64 nodes x 64 cols tile.
// W^T staged in padded LDS (stride K+4: 16B-aligned b128 reads, 2-way bank
// aliasing = free). Each thread owns a 4x4 tile: per 4-k step, 4 global
// float4 x-loads (broadcast across 16 lanes) + 4 ds_read_b128 + 64 fma.

template<int K>
__global__ __launch_bounds__(256)
void k_gemm_t(const float* __restrict__ xin, const float* __restrict__ Wg,
              const float* __restrict__ a_s, const float* __restrict__ a_d,
              float* __restrict__ h, float* __restrict__ es, float* __restrict__ ed) {
    __shared__ float wt[64][K + 4];   // wt[col][k] = Wg[k][col]
    const int t = threadIdx.x;
    const int lane = t & 63, wid = t >> 6;
    for (int k = wid; k < K; k += 4)
        wt[lane][k] = Wg[k * 64 + lane];
    __syncthreads();

    const int cg = t & 15, ng = t >> 4;
    const int c0 = cg * 4;
    const int node0 = blockIdx.x * 64 + ng * 4;
    if (node0 >= N_NODES) return;    // N_NODES % 4 == 0: all-or-nothing per thread
    const float* xrow = xin + (size_t)node0 * K;

    float acc[4][4];
    #pragma unroll
    for (int n = 0; n < 4; ++n)
        #pragma unroll
        for (int i = 0; i < 4; ++i) acc[n][i] = 0.f;

    #pragma unroll 4
    for (int k = 0; k < K; k += 4) {
        float4 xv[4], wv[4];
        #pragma unroll
        for (int n = 0; n < 4; ++n) xv[n] = *(const float4*)(xrow + n * K + k);
        #pragma unroll
        for (int i = 0; i < 4; ++i) wv[i] = *(const float4*)(&wt[c0 + i][k]);
        #pragma unroll
        for (int n = 0; n < 4; ++n) {
            #pragma unroll
            for (int i = 0; i < 4; ++i) {
                acc[n][i] = fmaf(xv[n].x, wv[i].x, acc[n][i]);
                acc[n][i] = fmaf(xv[n].y, wv[i].y, acc[n][i]);
                acc[n][i] = fmaf(xv[n].z, wv[i].z, acc[n][i]);
                acc[n][i] = fmaf(xv[n].w, wv[i].w, acc[n][i]);
            }
        }
    }

    const float4 as4 = *(const float4*)(a_s + c0);
    const float4 ad4 = *(const float4*)(a_d + c0);
    #pragma unroll
    for (int n = 0; n < 4; ++n) {
        float4 hv = make_float4(acc[n][0], acc[n][1], acc[n][2], acc[n][3]);
        *(float4*)(h + (size_t)(node0 + n) * D_HID + c0) = hv;
        float vs = acc[n][0] * as4.x + acc[n][1] * as4.y
                 + acc[n][2] * as4.z + acc[n][3] * as4.w;
        float vd = acc[n][0] * ad4.x + acc[n][1] * ad4.y
                 + acc[n][2] * ad4.z + acc[n][3] * ad4.w;
        #pragma unroll
        for (int off = 8; off; off >>= 1) {   // butterfly across the 16 col-lanes
            vs += __shfl_xor(vs, off);
            vd += __shfl_xor(vd, off);
        }
        if (cg == 0) { es[node0 + n] = vs; ed[node0 + n] = vd; }
    }
}

// ---------------- sparse: segment softmax + weighted aggregation ----------------
// one wave per destination node

template<bool RELU, bool WRITE_ALPHA>
__global__ __launch_bounds__(256)
void k_agg(const float* __restrict__ h, const float* __restrict__ es,
           const float* __restrict__ ed, const int* __restrict__ rowptr,
           const int* __restrict__ csr_src, const int* __restrict__ csr_eid,
           const float* __restrict__ bias, float* __restrict__ out,
           float* __restrict__ alpha_out) {
    int wave = threadIdx.x >> 6, lane = threadIdx.x & 63;
    int node = blockIdx.x * 4 + wave;
    if (node >= N_NODES) return;
    int lo  = __builtin_amdgcn_readfirstlane(rowptr[node]);
    int deg = __builtin_amdgcn_readfirstlane(rowptr[node + 1]) - lo;
    float edv = ed[node];

    if (deg <= 64) {
        // ---- fast path: lane-parallel logits, register-resident softmax ----
        int   s = 0, eid = 0;
        float e = -INFINITY;
        if (lane < deg) {
            s   = csr_src[lo + lane];
            if (WRITE_ALPHA) eid = csr_eid[lo + lane];
            e = es[s] + edv;
            e = (e >= 0.f) ? e : NEG_SLOPE * e;
        }
        float m = e;
        #pragma unroll
        for (int off = 32; off; off >>= 1) m = fmaxf(m, __shfl_xor(m, off));
        float ex = (lane < deg) ? __expf(e - m) : 0.f;
        float z = ex;
        #pragma unroll
        for (int off = 32; off; off >>= 1) z += __shfl_xor(z, off);
        float inv = 1.f / z;

        // 4 independent fma/load chains for memory-level parallelism
        float a0 = 0.f, a1 = 0.f, a2 = 0.f, a3 = 0.f;
        int j = 0;
        for (; j + 4 <= deg; j += 4) {
            int   s0 = __shfl(s, j),     s1 = __shfl(s, j + 1);
            int   s2 = __shfl(s, j + 2), s3 = __shfl(s, j + 3);
            float e0 = __shfl(ex, j),     e1 = __shfl(ex, j + 1);
            float e2 = __shfl(ex, j + 2), e3 = __shfl(ex, j + 3);
            a0 = fmaf(e0, h[s0 * D_HID + lane], a0);
            a1 = fmaf(e1, h[s1 * D_HID + lane], a1);
            a2 = fmaf(e2, h[s2 * D_HID + lane], a2);
            a3 = fmaf(e3, h[s3 * D_HID + lane], a3);
        }
        for (; j < deg; ++j) {
            int   sj  = __shfl(s, j);
            float exj = __shfl(ex, j);
            a0 = fmaf(exj, h[sj * D_HID + lane], a0);
        }
        float acc = (a0 + a1) + (a2 + a3);
        float res = fmaf(acc, inv, bias[lane]);
        if (RELU) res = fmaxf(res, 0.f);
        out[node * D_HID + lane] = res;
        if (WRITE_ALPHA && lane < deg) alpha_out[eid] = ex * inv;
    } else {
        // ---- fallback: serial 3-pass (degree > 64; effectively never) ----
        int hi = lo + deg;
        float m = -INFINITY;
        for (int j = lo; j < hi; ++j) {
            float e = es[csr_src[j]] + edv;
            e = (e >= 0.f) ? e : NEG_SLOPE * e;
            m = fmaxf(m, e);
        }
        float z = 0.f, acc = 0.f;
        for (int j = lo; j < hi; ++j) {
            int s = csr_src[j];
            float e = es[s] + edv;
            e = (e >= 0.f) ? e : NEG_SLOPE * e;
            float ex = __expf(e - m);
            z += ex;
            acc = fmaf(ex, h[s * D_HID + lane], acc);
        }
        float inv = 1.f / z;
        float res = fmaf(acc, inv, bias[lane]);
        if (RELU) res = fmaxf(res, 0.f);
        out[node * D_HID + lane] = res;
        if (WRITE_ALPHA) {
            for (int j = lo + lane; j < hi; j += 64) {
                int s = csr_src[j];
                float e = es[s] + edv;
                e = (e >= 0.f) ? e : NEG_SLOPE * e;
                alpha_out[csr_eid[j]] = __expf(e - m) * inv;
            }
        }
    }
}

// ---------------- launch ----------------

extern "C" void kernel_launch(void* const* d_in, const int* in_sizes, int n_in,
                              void* d_out, int out_size, void* d_ws, size_t ws_size,
                              hipStream_t stream) {
    const float* x    = (const float*)d_in[0];
    const int*   ei   = (const int*)d_in[1];
    const float* W1   = (const float*)d_in[2];
    const float* as1  = (const float*)d_in[3];
    const float* ad1  = (const float*)d_in[4];
    const float* b1   = (const float*)d_in[5];
    const float* W2   = (const float*)d_in[6];
    const float* as2  = (const float*)d_in[7];
    const float* ad2  = (const float*)d_in[8];
    const float* b2   = (const float*)d_in[9];
    float* out = (float*)d_out;

    // carve workspace (~34 MB)
    size_t off = 0;
    auto carve = [&](size_t bytes) -> void* {
        void* p = (char*)d_ws + off;
        off += (bytes + 255) & ~(size_t)255;
        return p;
    };
    int*   cursor   = (int*)carve((size_t)N_NODES * 4);          // counts, then cursor
    int*   rowptr   = (int*)carve((size_t)(N_NODES + 1) * 4);
    int*   blocksum = (int*)carve((size_t)SCAN_NB * 4);
    int*   csr_src  = (int*)carve((size_t)E_TOT * 4);
    int*   csr_eid  = (int*)carve((size_t)E_TOT * 4);
    float* h1       = (float*)carve((size_t)N_NODES * D_HID * 4); // reused as h2lin
    float* h1a      = (float*)carve((size_t)N_NODES * D_HID * 4);
    float* es       = (float*)carve((size_t)N_NODES * 4);         // reused layer 2
    float* edv      = (float*)carve((size_t)N_NODES * 4);         // reused layer 2

    float* out_ei    = out;                     // [2*E_TOT]
    float* out_alpha = out + 2 * (size_t)E_TOT; // [E_TOT]
    float* out_h2    = out + 3 * (size_t)E_TOT; // [N*64]

    const int eb = (E_TOT + 255) / 256;
    const int nb = (N_NODES + 3) / 4;
    const int gb = (N_NODES + 63) / 64;        // 782 GEMM tiles

    // CSR build (shared by both layers)
    hipMemsetAsync(cursor, 0, (size_t)N_NODES * 4, stream);
    k_hist_ei<<<eb, 256, 0, stream>>>(ei, cursor, out_ei);
    k_scan_a<<<SCAN_NB, SCAN_B, 0, stream>>>(cursor, blocksum);
    k_scan_b<<<1, SCAN_B, 0, stream>>>(blocksum, rowptr);
    k_scan_c<<<SCAN_NB, SCAN_B, 0, stream>>>(cursor, blocksum, rowptr);
    k_scatter<<<eb, 256, 0, stream>>>(ei, cursor, csr_src, csr_eid);

    // layer 1
    k_gemm_t<D_IN><<<gb, 256, 0, stream>>>(x, W1, as1, ad1, h1, es, edv);
    k_agg<true, true><<<nb, 256, 0, stream>>>(h1, es, edv, rowptr, csr_src, csr_eid,
                                              b1, h1a, out_alpha);
    // layer 2 (h2lin aliases h1; es/edv reused)
    k_gemm_t<D_HID><<<gb, 256, 0, stream>>>(h1a, W2, as2, ad2, h1, es, edv);
    k_agg<false, false><<<nb, 256, 0, stream>>>(h1, es, edv, rowptr, csr_src, csr_eid,
                                                b2, out_h2, nullptr);
}